// Round 1
// baseline (654.629 us; speedup 1.0000x reference)
//
#include <hip/hip_runtime.h>
#include <math.h>

#define N_NODES 32768
#define N_EDGES 262144
#define OUTC 54   // 16 emb + 38 msg

// ---------------- Kernel 1: node embeddings -----------------
// node_emb = ((x @ W_emb1)/sqrt(10) @ W_emb2)/8, written to out[:, 0:16]
__global__ __launch_bounds__(256) void node_emb_kernel(
    const float* __restrict__ x, const float* __restrict__ W1,
    const float* __restrict__ W2, float* __restrict__ out)
{
    int n = blockIdx.x * blockDim.x + threadIdx.x;
    if (n >= N_NODES) return;
    const float inv10 = 0.31622776601683794f; // 1/sqrt(10)
    const float inv64 = 0.125f;               // 1/sqrt(64)

    float xr[10];
    #pragma unroll
    for (int i = 0; i < 10; ++i) xr[i] = x[n*10 + i];

    float t[64];
    #pragma unroll
    for (int k = 0; k < 64; ++k) {
        float acc = 0.f;
        #pragma unroll
        for (int i = 0; i < 10; ++i) acc = fmaf(xr[i], W1[i*64 + k], acc);
        t[k] = acc * inv10;
    }

    float e[16];
    #pragma unroll
    for (int j = 0; j < 16; ++j) e[j] = 0.f;
    #pragma unroll
    for (int k = 0; k < 64; ++k) {
        float tk = t[k];
        #pragma unroll
        for (int j = 0; j < 16; ++j) e[j] = fmaf(tk, W2[k*16 + j], e[j]);
    }
    #pragma unroll
    for (int j = 0; j < 16; ++j) out[n*OUTC + j] = e[j] * inv64;
}

// ---------------- Kernel 2: per-edge tensor product + scatter -----------------
__global__ __launch_bounds__(256) void edge_kernel(
    const float* __restrict__ pos, const int* __restrict__ ei,
    const float* __restrict__ Wt1, const float* __restrict__ Wt2,
    float* out)
{
    int e = blockIdx.x * blockDim.x + threadIdx.x;
    if (e >= N_EDGES) return;

    int src = ei[e];
    int dst = ei[N_EDGES + e];

    float px = pos[dst*3+0] - pos[src*3+0];
    float py = pos[dst*3+1] - pos[src*3+1];
    float pz = pos[dst*3+2] - pos[src*3+2];
    float dist = sqrtf(px*px + py*py + pz*pz + 1e-12f);
    float rinv = 1.0f / dist;
    float ux = px*rinv, uy = py*rinv, uz = pz*rinv;

    // radial embedding: centers (j+1)*5/21, j=0..19; step=5/21.
    // d_j = dist/step - (j+1); |d_j| < 1 holds for at most j0=m-1, j1=m.
    const float step = 5.0f / 21.0f;
    float tt = dist / step;
    int m  = (int)floorf(tt);
    int j0 = m - 1;             // d0 = tt - m in [0,1)
    int j1 = m;                 // d1 = d0 - 1 in [-1,0)
    float d0 = tt - (float)m;
    float d1 = d0 - 1.0f;
    const float sq20 = 4.47213595499958f;   // sqrt(20)

    float f0 = 0.f, f1 = 0.f;
    if (j0 >= 0 && j0 < 20)
        f0 = 1.14136f * expf(2.0f - 1.0f/(1.0f + d0) - 1.0f/(1.0f - d0)) * sq20;
    if (j1 >= 0 && j1 < 20 && d1 > -1.0f)
        f1 = 1.14136f * expf(2.0f - 1.0f/(1.0f + d1) - 1.0f/(1.0f - d1)) * sq20;

    if (f0 == 0.f && f1 == 0.f) return;   // zero contribution (dist out of range)

    // clamp for safe loads (masked values already 0)
    j0 = j0 < 0 ? 0 : (j0 > 19 ? 19 : j0);
    j1 = j1 < 0 ? 0 : (j1 > 19 ? 19 : j1);
    const float* w1a = Wt1 + j0*64;
    const float* w1b = Wt1 + j1*64;

    // gather z = node_emb[src] from the already-written output columns
    float z[16];
    #pragma unroll
    for (int i = 0; i < 16; ++i) z[i] = out[src*OUTC + i];

    const float rsq20 = 0.22360679774997896f; // 1/sqrt(20)
    const float snorm = 1.679177f;

    float accS[16], accV[4], accT[2];
    #pragma unroll
    for (int u = 0; u < 16; ++u) accS[u] = 0.f;
    #pragma unroll
    for (int u = 0; u < 4; ++u) accV[u] = 0.f;
    #pragma unroll
    for (int u = 0; u < 2; ++u) accT[u] = 0.f;

    for (int k = 0; k < 64; ++k) {
        // h_k = SILU_NORM * silu((f0*W1[j0,k] + f1*W1[j1,k])/sqrt(20))
        float a = fmaf(f0, w1a[k], f1 * w1b[k]) * rsq20;
        float hk = snorm * a / (1.0f + expf(-a));

        const float* row = Wt2 + k*352;   // wave-uniform -> scalar loads

        float tmp[16];
        #pragma unroll
        for (int u = 0; u < 16; ++u) tmp[u] = 0.f;
        #pragma unroll
        for (int i = 0; i < 16; ++i) {
            float zi = z[i];
            #pragma unroll
            for (int u = 0; u < 16; ++u)
                tmp[u] = fmaf(zi, row[i*16 + u], tmp[u]);
        }
        #pragma unroll
        for (int u = 0; u < 16; ++u) accS[u] = fmaf(hk, tmp[u], accS[u]);

        float tv[4] = {0.f, 0.f, 0.f, 0.f};
        #pragma unroll
        for (int i = 0; i < 16; ++i) {
            float zi = z[i];
            #pragma unroll
            for (int u = 0; u < 4; ++u)
                tv[u] = fmaf(zi, row[256 + i*4 + u], tv[u]);
        }
        #pragma unroll
        for (int u = 0; u < 4; ++u) accV[u] = fmaf(hk, tv[u], accV[u]);

        float tw[2] = {0.f, 0.f};
        #pragma unroll
        for (int i = 0; i < 16; ++i) {
            float zi = z[i];
            #pragma unroll
            for (int u = 0; u < 2; ++u)
                tw[u] = fmaf(zi, row[320 + i*2 + u], tw[u]);
        }
        #pragma unroll
        for (int u = 0; u < 2; ++u) accT[u] = fmaf(hk, tw[u], accT[u]);
    }

    // combined scale: (w /= sqrt(64)) * (inv = 1/sqrt(16)) * (1/sqrt(num_neighbors=8))
    const float sc = 0.125f * 0.25f * 0.35355339059327373f;

    const float s3  = 1.7320508075688772f;  // sqrt(3)
    const float s15 = 3.872983346207417f;   // sqrt(15)
    const float s5  = 2.23606797749979f;    // sqrt(5)
    float sh1x = s3*ux, sh1y = s3*uy, sh1z = s3*uz;
    float sh2[5];
    sh2[0] = s15 * ux * uz;
    sh2[1] = s15 * ux * uy;
    sh2[2] = s5 * (uy*uy - 0.5f*(ux*ux + uz*uz));
    sh2[3] = s15 * uy * uz;
    sh2[4] = 0.5f * s15 * (uz*uz - ux*ux);

    float* orow = out + dst*OUTC + 16;
    #pragma unroll
    for (int u = 0; u < 16; ++u) atomicAdd(&orow[u], accS[u] * sc);
    #pragma unroll
    for (int u = 0; u < 4; ++u) {
        float v = accV[u] * sc;
        atomicAdd(&orow[16 + u*3 + 0], v * sh1x);
        atomicAdd(&orow[16 + u*3 + 1], v * sh1y);
        atomicAdd(&orow[16 + u*3 + 2], v * sh1z);
    }
    #pragma unroll
    for (int u = 0; u < 2; ++u) {
        float v = accT[u] * sc;
        #pragma unroll
        for (int mm = 0; mm < 5; ++mm)
            atomicAdd(&orow[28 + u*5 + mm], v * sh2[mm]);
    }
}

extern "C" void kernel_launch(void* const* d_in, const int* in_sizes, int n_in,
                              void* d_out, int out_size, void* d_ws, size_t ws_size,
                              hipStream_t stream) {
    const float* x   = (const float*)d_in[0];
    const float* pos = (const float*)d_in[1];
    const int*   ei  = (const int*)d_in[2];
    const float* We1 = (const float*)d_in[3];
    const float* We2 = (const float*)d_in[4];
    const float* Wt1 = (const float*)d_in[5];
    const float* Wt2 = (const float*)d_in[6];
    float* out = (float*)d_out;

    hipMemsetAsync(out, 0, (size_t)out_size * sizeof(float), stream);
    node_emb_kernel<<<N_NODES/256, 256, 0, stream>>>(x, We1, We2, out);
    edge_kernel<<<N_EDGES/256, 256, 0, stream>>>(pos, ei, Wt1, Wt2, out);
}

// Round 2
// 247.257 us; speedup vs baseline: 2.6476x; 2.6476x over previous
//
#include <hip/hip_runtime.h>
#include <math.h>

#define N_NODES 32768
#define N_EDGES 262144
#define OUTC 54      // 16 emb + 38 msg
#define TPW  40      // tp row stride in floats (38 used, 16B-aligned)

// ---------------- Kernel 1: node embeddings -----------------
__global__ __launch_bounds__(256) void node_emb_kernel(
    const float* __restrict__ x, const float* __restrict__ W1,
    const float* __restrict__ W2, float* __restrict__ out)
{
    int n = blockIdx.x * blockDim.x + threadIdx.x;
    if (n >= N_NODES) return;
    const float inv10 = 0.31622776601683794f;
    const float inv64 = 0.125f;

    float xr[10];
    #pragma unroll
    for (int i = 0; i < 10; ++i) xr[i] = x[n*10 + i];

    float t[64];
    #pragma unroll
    for (int k = 0; k < 64; ++k) {
        float acc = 0.f;
        #pragma unroll
        for (int i = 0; i < 10; ++i) acc = fmaf(xr[i], W1[i*64 + k], acc);
        t[k] = acc * inv10;
    }

    float e[16];
    #pragma unroll
    for (int j = 0; j < 16; ++j) e[j] = 0.f;
    #pragma unroll
    for (int k = 0; k < 64; ++k) {
        float tk = t[k];
        #pragma unroll
        for (int j = 0; j < 16; ++j) e[j] = fmaf(tk, W2[k*16 + j], e[j]);
    }
    #pragma unroll
    for (int j = 0; j < 16; ++j) out[n*OUTC + j] = e[j] * inv64;
}

// ---------------- CSR build -----------------
__global__ __launch_bounds__(256) void count_kernel(
    const int* __restrict__ ei, int* __restrict__ cnt)
{
    int e = blockIdx.x * blockDim.x + threadIdx.x;
    if (e < N_EDGES) atomicAdd(&cnt[ei[N_EDGES + e]], 1);
}

// single block, 1024 threads, 32 elements each. counts live in `cursor`;
// writes exclusive starts to `start` and resets `cursor` to the starts.
__global__ __launch_bounds__(1024) void scan_kernel(
    int* __restrict__ cursor, int* __restrict__ start)
{
    __shared__ int partial[1024];
    int tid = threadIdx.x;
    int base = tid * 32;
    int v[32];
    int s = 0;
    #pragma unroll
    for (int j = 0; j < 32; ++j) { v[j] = cursor[base + j]; s += v[j]; }
    partial[tid] = s;
    __syncthreads();
    for (int off = 1; off < 1024; off <<= 1) {
        int t = (tid >= off) ? partial[tid - off] : 0;
        __syncthreads();
        partial[tid] += t;
        __syncthreads();
    }
    int run = (tid > 0) ? partial[tid - 1] : 0;
    #pragma unroll
    for (int j = 0; j < 32; ++j) {
        start[base + j] = run;
        cursor[base + j] = run;
        run += v[j];
    }
    if (tid == 1023) start[N_NODES] = run;   // == N_EDGES
}

// ---------------- Kernel 3: per-edge tensor product, coalesced write ---------
__global__ __launch_bounds__(256) void edge_kernel_csr(
    const float* __restrict__ pos, const int* __restrict__ ei,
    const float* __restrict__ Wt1, const float* __restrict__ Wt2,
    const float* __restrict__ out,          // node_emb already in cols 0..15
    float* __restrict__ tp, int* __restrict__ cursor, int* __restrict__ elist)
{
    int e = blockIdx.x * blockDim.x + threadIdx.x;
    if (e >= N_EDGES) return;

    int src = ei[e];
    int dst = ei[N_EDGES + e];

    // allocate slot early (latency overlaps with compute below)
    int slot = atomicAdd(&cursor[dst], 1);
    elist[slot] = e;

    float* trow = tp + (size_t)e * TPW;

    float px = pos[dst*3+0] - pos[src*3+0];
    float py = pos[dst*3+1] - pos[src*3+1];
    float pz = pos[dst*3+2] - pos[src*3+2];
    float dist = sqrtf(px*px + py*py + pz*pz + 1e-12f);
    float rinv = 1.0f / dist;
    float ux = px*rinv, uy = py*rinv, uz = pz*rinv;

    const float step = 5.0f / 21.0f;
    float tt = dist / step;
    int m  = (int)floorf(tt);
    int j0 = m - 1;
    int j1 = m;
    float d0 = tt - (float)m;
    float d1 = d0 - 1.0f;
    const float sq20 = 4.47213595499958f;

    float f0 = 0.f, f1 = 0.f;
    if (j0 >= 0 && j0 < 20)
        f0 = 1.14136f * expf(2.0f - 1.0f/(1.0f + d0) - 1.0f/(1.0f - d0)) * sq20;
    if (j1 >= 0 && j1 < 20 && d1 > -1.0f)
        f1 = 1.14136f * expf(2.0f - 1.0f/(1.0f + d1) - 1.0f/(1.0f - d1)) * sq20;

    if (f0 == 0.f && f1 == 0.f) {
        // zero contribution: write zero row
        float4 zz = make_float4(0.f, 0.f, 0.f, 0.f);
        #pragma unroll
        for (int q = 0; q < 9; ++q)
            *reinterpret_cast<float4*>(trow + q*4) = zz;
        trow[36] = 0.f; trow[37] = 0.f;
        return;
    }

    j0 = j0 < 0 ? 0 : (j0 > 19 ? 19 : j0);
    j1 = j1 < 0 ? 0 : (j1 > 19 ? 19 : j1);
    const float* w1a = Wt1 + j0*64;
    const float* w1b = Wt1 + j1*64;

    float z[16];
    #pragma unroll
    for (int i = 0; i < 16; ++i) z[i] = out[src*OUTC + i];

    const float rsq20 = 0.22360679774997896f;
    const float snorm = 1.679177f;

    float accS[16], accV[4], accT[2];
    #pragma unroll
    for (int u = 0; u < 16; ++u) accS[u] = 0.f;
    #pragma unroll
    for (int u = 0; u < 4; ++u) accV[u] = 0.f;
    #pragma unroll
    for (int u = 0; u < 2; ++u) accT[u] = 0.f;

    for (int k = 0; k < 64; ++k) {
        float a = fmaf(f0, w1a[k], f1 * w1b[k]) * rsq20;
        float hk = snorm * a / (1.0f + expf(-a));

        const float* row = Wt2 + k*352;   // wave-uniform -> scalar loads

        float tmp[16];
        #pragma unroll
        for (int u = 0; u < 16; ++u) tmp[u] = 0.f;
        #pragma unroll
        for (int i = 0; i < 16; ++i) {
            float zi = z[i];
            #pragma unroll
            for (int u = 0; u < 16; ++u)
                tmp[u] = fmaf(zi, row[i*16 + u], tmp[u]);
        }
        #pragma unroll
        for (int u = 0; u < 16; ++u) accS[u] = fmaf(hk, tmp[u], accS[u]);

        float tv[4] = {0.f, 0.f, 0.f, 0.f};
        #pragma unroll
        for (int i = 0; i < 16; ++i) {
            float zi = z[i];
            #pragma unroll
            for (int u = 0; u < 4; ++u)
                tv[u] = fmaf(zi, row[256 + i*4 + u], tv[u]);
        }
        #pragma unroll
        for (int u = 0; u < 4; ++u) accV[u] = fmaf(hk, tv[u], accV[u]);

        float tw[2] = {0.f, 0.f};
        #pragma unroll
        for (int i = 0; i < 16; ++i) {
            float zi = z[i];
            #pragma unroll
            for (int u = 0; u < 2; ++u)
                tw[u] = fmaf(zi, row[320 + i*2 + u], tw[u]);
        }
        #pragma unroll
        for (int u = 0; u < 2; ++u) accT[u] = fmaf(hk, tw[u], accT[u]);
    }

    const float sc = 0.125f * 0.25f * 0.35355339059327373f;
    const float s3  = 1.7320508075688772f;
    const float s15 = 3.872983346207417f;
    const float s5  = 2.23606797749979f;
    float sh1x = s3*ux, sh1y = s3*uy, sh1z = s3*uz;
    float sh2[5];
    sh2[0] = s15 * ux * uz;
    sh2[1] = s15 * ux * uy;
    sh2[2] = s5 * (uy*uy - 0.5f*(ux*ux + uz*uz));
    sh2[3] = s15 * uy * uz;
    sh2[4] = 0.5f * s15 * (uz*uz - ux*ux);

    float vals[38];
    #pragma unroll
    for (int u = 0; u < 16; ++u) vals[u] = accS[u] * sc;
    #pragma unroll
    for (int u = 0; u < 4; ++u) {
        float v = accV[u] * sc;
        vals[16 + u*3 + 0] = v * sh1x;
        vals[16 + u*3 + 1] = v * sh1y;
        vals[16 + u*3 + 2] = v * sh1z;
    }
    #pragma unroll
    for (int u = 0; u < 2; ++u) {
        float v = accT[u] * sc;
        #pragma unroll
        for (int mm = 0; mm < 5; ++mm)
            vals[28 + u*5 + mm] = v * sh2[mm];
    }

    #pragma unroll
    for (int q = 0; q < 9; ++q)
        *reinterpret_cast<float4*>(trow + q*4) =
            make_float4(vals[q*4+0], vals[q*4+1], vals[q*4+2], vals[q*4+3]);
    trow[36] = vals[36];
    trow[37] = vals[37];
}

// ---------------- Kernel 4: gather segment-sum -----------------
__global__ __launch_bounds__(256) void gather_kernel(
    const float* __restrict__ tp, const int* __restrict__ start,
    const int* __restrict__ elist, float* __restrict__ out)
{
    int wave = threadIdx.x >> 6;
    int lane = threadIdx.x & 63;
    int n = blockIdx.x * 4 + wave;
    if (n >= N_NODES) return;
    int s0 = start[n], s1 = start[n+1];
    if (lane < 38) {
        float acc = 0.f;
        for (int j = s0; j < s1; ++j) {
            int e = elist[j];
            acc += tp[(size_t)e * TPW + lane];
        }
        out[n*OUTC + 16 + lane] = acc;
    }
}

// ---------------- fallback (atomics) if ws too small -----------------
__global__ __launch_bounds__(256) void edge_kernel_atomic(
    const float* __restrict__ pos, const int* __restrict__ ei,
    const float* __restrict__ Wt1, const float* __restrict__ Wt2,
    float* out)
{
    int e = blockIdx.x * blockDim.x + threadIdx.x;
    if (e >= N_EDGES) return;
    int src = ei[e];
    int dst = ei[N_EDGES + e];
    float px = pos[dst*3+0] - pos[src*3+0];
    float py = pos[dst*3+1] - pos[src*3+1];
    float pz = pos[dst*3+2] - pos[src*3+2];
    float dist = sqrtf(px*px + py*py + pz*pz + 1e-12f);
    float rinv = 1.0f / dist;
    float ux = px*rinv, uy = py*rinv, uz = pz*rinv;
    const float step = 5.0f / 21.0f;
    float tt = dist / step;
    int m  = (int)floorf(tt);
    int j0 = m - 1, j1 = m;
    float d0 = tt - (float)m, d1 = d0 - 1.0f;
    const float sq20 = 4.47213595499958f;
    float f0 = 0.f, f1 = 0.f;
    if (j0 >= 0 && j0 < 20)
        f0 = 1.14136f * expf(2.0f - 1.0f/(1.0f + d0) - 1.0f/(1.0f - d0)) * sq20;
    if (j1 >= 0 && j1 < 20 && d1 > -1.0f)
        f1 = 1.14136f * expf(2.0f - 1.0f/(1.0f + d1) - 1.0f/(1.0f - d1)) * sq20;
    if (f0 == 0.f && f1 == 0.f) return;
    j0 = j0 < 0 ? 0 : (j0 > 19 ? 19 : j0);
    j1 = j1 < 0 ? 0 : (j1 > 19 ? 19 : j1);
    const float* w1a = Wt1 + j0*64;
    const float* w1b = Wt1 + j1*64;
    float z[16];
    #pragma unroll
    for (int i = 0; i < 16; ++i) z[i] = out[src*OUTC + i];
    const float rsq20 = 0.22360679774997896f;
    const float snorm = 1.679177f;
    float accS[16], accV[4], accT[2];
    #pragma unroll
    for (int u = 0; u < 16; ++u) accS[u] = 0.f;
    #pragma unroll
    for (int u = 0; u < 4; ++u) accV[u] = 0.f;
    #pragma unroll
    for (int u = 0; u < 2; ++u) accT[u] = 0.f;
    for (int k = 0; k < 64; ++k) {
        float a = fmaf(f0, w1a[k], f1 * w1b[k]) * rsq20;
        float hk = snorm * a / (1.0f + expf(-a));
        const float* row = Wt2 + k*352;
        float tmp[16];
        #pragma unroll
        for (int u = 0; u < 16; ++u) tmp[u] = 0.f;
        #pragma unroll
        for (int i = 0; i < 16; ++i) {
            float zi = z[i];
            #pragma unroll
            for (int u = 0; u < 16; ++u) tmp[u] = fmaf(zi, row[i*16 + u], tmp[u]);
        }
        #pragma unroll
        for (int u = 0; u < 16; ++u) accS[u] = fmaf(hk, tmp[u], accS[u]);
        float tv[4] = {0.f,0.f,0.f,0.f};
        #pragma unroll
        for (int i = 0; i < 16; ++i) {
            float zi = z[i];
            #pragma unroll
            for (int u = 0; u < 4; ++u) tv[u] = fmaf(zi, row[256 + i*4 + u], tv[u]);
        }
        #pragma unroll
        for (int u = 0; u < 4; ++u) accV[u] = fmaf(hk, tv[u], accV[u]);
        float tw[2] = {0.f,0.f};
        #pragma unroll
        for (int i = 0; i < 16; ++i) {
            float zi = z[i];
            #pragma unroll
            for (int u = 0; u < 2; ++u) tw[u] = fmaf(zi, row[320 + i*2 + u], tw[u]);
        }
        #pragma unroll
        for (int u = 0; u < 2; ++u) accT[u] = fmaf(hk, tw[u], accT[u]);
    }
    const float sc = 0.125f * 0.25f * 0.35355339059327373f;
    const float s3  = 1.7320508075688772f;
    const float s15 = 3.872983346207417f;
    const float s5  = 2.23606797749979f;
    float sh1x = s3*ux, sh1y = s3*uy, sh1z = s3*uz;
    float sh2[5];
    sh2[0] = s15 * ux * uz;
    sh2[1] = s15 * ux * uy;
    sh2[2] = s5 * (uy*uy - 0.5f*(ux*ux + uz*uz));
    sh2[3] = s15 * uy * uz;
    sh2[4] = 0.5f * s15 * (uz*uz - ux*ux);
    float* orow = out + dst*OUTC + 16;
    #pragma unroll
    for (int u = 0; u < 16; ++u) atomicAdd(&orow[u], accS[u] * sc);
    #pragma unroll
    for (int u = 0; u < 4; ++u) {
        float v = accV[u] * sc;
        atomicAdd(&orow[16 + u*3 + 0], v * sh1x);
        atomicAdd(&orow[16 + u*3 + 1], v * sh1y);
        atomicAdd(&orow[16 + u*3 + 2], v * sh1z);
    }
    #pragma unroll
    for (int u = 0; u < 2; ++u) {
        float v = accT[u] * sc;
        #pragma unroll
        for (int mm = 0; mm < 5; ++mm)
            atomicAdd(&orow[28 + u*5 + mm], v * sh2[mm]);
    }
}

extern "C" void kernel_launch(void* const* d_in, const int* in_sizes, int n_in,
                              void* d_out, int out_size, void* d_ws, size_t ws_size,
                              hipStream_t stream) {
    const float* x   = (const float*)d_in[0];
    const float* pos = (const float*)d_in[1];
    const int*   ei  = (const int*)d_in[2];
    const float* We1 = (const float*)d_in[3];
    const float* We2 = (const float*)d_in[4];
    const float* Wt1 = (const float*)d_in[5];
    const float* Wt2 = (const float*)d_in[6];
    float* out = (float*)d_out;

    // workspace layout
    float* tp    = (float*)d_ws;                               // N_EDGES*TPW floats
    int*   startp= (int*)(tp + (size_t)N_EDGES * TPW);         // N_NODES+1
    int*   cursor= startp + (N_NODES + 1);                     // N_NODES
    int*   elist = cursor + N_NODES;                           // N_EDGES
    size_t need  = (size_t)N_EDGES * TPW * 4
                 + (size_t)(N_NODES + 1 + N_NODES + N_EDGES) * 4;

    node_emb_kernel<<<N_NODES/256, 256, 0, stream>>>(x, We1, We2, out);

    if (ws_size >= need) {
        hipMemsetAsync(cursor, 0, (size_t)N_NODES * sizeof(int), stream);
        count_kernel<<<N_EDGES/256, 256, 0, stream>>>(ei, cursor);
        scan_kernel<<<1, 1024, 0, stream>>>(cursor, startp);
        edge_kernel_csr<<<N_EDGES/256, 256, 0, stream>>>(pos, ei, Wt1, Wt2, out,
                                                         tp, cursor, elist);
        gather_kernel<<<N_NODES/4, 256, 0, stream>>>(tp, startp, elist, out);
    } else {
        // fallback: atomic scatter directly into out
        hipMemsetAsync(out, 0, (size_t)out_size * sizeof(float), stream);
        node_emb_kernel<<<N_NODES/256, 256, 0, stream>>>(x, We1, We2, out);
        edge_kernel_atomic<<<N_EDGES/256, 256, 0, stream>>>(pos, ei, Wt1, Wt2, out);
    }
}